// Round 11
// baseline (281.406 us; speedup 1.0000x reference)
//
#include <hip/hip_runtime.h>
#include <hip/hip_bf16.h>
#include <hip/hip_fp16.h>

#define B_ 8
#define N_ 10000
#define E_ 160000
#define D_ 256
#define H_ 128
#define SLOPE 0.2f
#define NCHUNK 100  // node chunks for dense weighted sum (100 nodes/chunk, 800 blocks)

// edge-sort config
#define NB_ 64            // histogram/scatter blocks
#define EPB_ (E_ / NB_)   // 2500 edges per block
#define BINS_ 256         // 16 dst-buckets x 16 src-buckets
#define NPB_ (N_ / 16)    // 625 nodes per bucket
#define SUBS_ 8           // k3f sub-splits per bucket
#define CANONB_ 313       // kprep canon blocks (covers B_*N_=80000)

// softmax stats config
#define SB_ 256           // stat blocks
#define SEB_ (E_ / SB_)   // 625 edges per stat block

typedef __attribute__((ext_vector_type(8))) _Float16 v8h;
typedef __attribute__((ext_vector_type(4))) _Float16 v4h;
typedef __attribute__((ext_vector_type(2))) _Float16 v2h;
typedef __attribute__((ext_vector_type(4))) float f32x4;

static __device__ __forceinline__ float dot2f(v2h a, v2h b, float c) {
#if __has_builtin(__builtin_amdgcn_fdot2)
    return __builtin_amdgcn_fdot2(a, b, c, false);
#else
    return fmaf((float)a.y, (float)b.y, fmaf((float)a.x, (float)b.x, c));
#endif
}

// per-block input-format detect (wave 0 ballots, LDS broadcast). sfl[0]=f_e, sfl[1]=f_m.
static __device__ __forceinline__ void block_flags(const int* __restrict__ eidx_raw,
                                                   const unsigned int* __restrict__ mask32,
                                                   int tid, int* sfl) {
    if (tid < 64) {
        unsigned long long oddnz = __ballot(eidx_raw[2 * tid + 1] != 0);
        unsigned long long mgt1  = __ballot(mask32[tid] > 1u);
        if (tid == 0) {
            sfl[0] = (oddnz == 0ull) ? 1 : 0;  // edge_index is int64
            sfl[1] = (mgt1 != 0ull) ? 1 : 0;   // mask is 1-byte bool
        }
    }
    __syncthreads();
}

// ---------------------------------------------------------------- kprep: canon (313) || hist-from-raw (64) || mask count (8)
__global__ __launch_bounds__(256) void kprep(const int* __restrict__ eidx_raw,
                                             const unsigned char* __restrict__ mask8,
                                             const unsigned int* __restrict__ mask32,
                                             const float* __restrict__ W1,
                                             const float* __restrict__ b1,
                                             const float* __restrict__ W2,
                                             unsigned char* __restrict__ cmT,
                                             __half* __restrict__ Wt,
                                             __half* __restrict__ b1h,
                                             __half* __restrict__ w2h,
                                             int* __restrict__ cnti,
                                             int* __restrict__ hpart) {
    const int tid = threadIdx.x;
    __shared__ int sfl[2];

    if (blockIdx.x < CANONB_) {  // ---- canon role: mask transpose + weight conversion
        block_flags(eidx_raw, mask32, tid, sfl);   // has __syncthreads
        const int f_m = sfl[1];
        const int i = blockIdx.x * 256 + tid;
        if (i < B_ * N_) {
            unsigned char v = f_m ? (unsigned char)(mask8[i] != 0)
                                  : (unsigned char)(mask32[i] != 0u);
            const int b = i / N_;
            const int n = i - b * N_;
            cmT[n * 8 + b] = v;
        }
        if (i < 2 * 256 * 128) {  // W1 -> fp16 transposed
            const int f = i & 127;
            const int row = i >> 7;       // 0..511
            const int c = row >> 8, k = row & 255;
            Wt[((c * 128 + f) * 256) + k] = __float2half(W1[row * 128 + f]);
        }
        if (i < 128) {
            b1h[i] = __float2half(b1[i]);
            w2h[i] = __float2half(W2[i]);
        }
    } else if (blockIdx.x < CANONB_ + NB_) {  // ---- hist role (reads raw edges, inline detect)
        block_flags(eidx_raw, mask32, tid, sfl);
        const int f_e = sfl[0];
        __shared__ int h[BINS_];
        h[tid] = 0;
        __syncthreads();
        const int hb = blockIdx.x - CANONB_;
        const int base = hb * EPB_;
        for (int i = tid; i < EPB_; i += 256) {
            const int e = base + i;
            const int s = f_e ? eidx_raw[2 * e] : eidx_raw[e];
            const int d = f_e ? eidx_raw[2 * (E_ + e)] : eidx_raw[E_ + e];
            const int bin = (d / NPB_) * 16 + s / NPB_;
            atomicAdd(&h[bin], 1);
        }
        __syncthreads();
        hpart[hb * BINS_ + tid] = h[tid];
    } else {                     // ---- mask count role (8 blocks, one per batch)
        block_flags(eidx_raw, mask32, tid, sfl);
        const int f_m = sfl[1];
        const int b = blockIdx.x - CANONB_ - NB_;
        int c = 0;
        for (int i = tid; i < N_; i += 256) {
            const int gi = b * N_ + i;
            c += (f_m ? (mask8[gi] != 0) : (mask32[gi] != 0u)) ? 1 : 0;
        }
        __shared__ int red[256];
        red[tid] = c;
        __syncthreads();
        for (int s = 128; s > 0; s >>= 1) {
            if (tid < s) red[tid] += red[tid + s];
            __syncthreads();
        }
        if (tid == 0) cnti[b] = red[0];
    }
}

// ---------------------------------------------------------------- edge sort: prefix (+ bucket starts)
__global__ __launch_bounds__(256) void kprefix(const int* __restrict__ hpart,
                                               int* __restrict__ offsetG,
                                               int* __restrict__ bstart) {
    __shared__ int cnt[BINS_];
    __shared__ int excl[BINS_];
    const int bin = threadIdx.x;
    int c = 0;
    for (int b = 0; b < NB_; b++) c += hpart[b * BINS_ + bin];
    cnt[bin] = c;
    __syncthreads();
    if (bin == 0) {
        int r = 0;
        for (int i = 0; i < BINS_; i++) { excl[i] = r; r += cnt[i]; }
    }
    __syncthreads();
    if ((bin & 15) == 0) bstart[bin >> 4] = excl[bin];
    if (bin == 0) bstart[16] = E_;
    int run = excl[bin];
    for (int b = 0; b < NB_; b++) {
        offsetG[b * BINS_ + bin] = run;
        run += hpart[b * BINS_ + bin];
    }
}

// ---------------------------------------------------------------- MEGA: k1 MFMA GEMM (1250 blocks) || scatter (64 blocks, raw edges)
// ps/pd layout: [b][n][128] fp16
__global__ __launch_bounds__(256) void k1_mfma(const float* __restrict__ X,
                                               const __half* __restrict__ Wt,
                                               __half* __restrict__ ps,
                                               __half* __restrict__ pd,
                                               const int* __restrict__ eidx_raw,
                                               const unsigned int* __restrict__ mask32,
                                               const int* __restrict__ offsetG,
                                               int4* __restrict__ esort) {
    const int tid = threadIdx.x;
    // union: staging dbuf Xs[2][64*40] (10240B) | epilogue tile T[64][136] (17408B) | scatter loc[256]
    __shared__ __align__(16) char smem[64 * 136 * 2];

    if (blockIdx.x >= 1250) {  // ---- scatter role (inline format detect, no ce)
        __shared__ int sfl[2];
        block_flags(eidx_raw, mask32, tid, sfl);
        const int f_e = sfl[0];
        int* loc = (int*)smem;
        const int sb = blockIdx.x - 1250;
        loc[tid] = offsetG[sb * BINS_ + tid];
        __syncthreads();
        const int base = sb * EPB_;
        for (int i = tid; i < EPB_; i += 256) {
            const int e = base + i;
            const int s = f_e ? eidx_raw[2 * e] : eidx_raw[e];
            const int d = f_e ? eidx_raw[2 * (E_ + e)] : eidx_raw[E_ + e];
            const int bin = (d / NPB_) * 16 + s / NPB_;
            const int pos = atomicAdd(&loc[bin], 1);
            esort[pos] = make_int4(s, d, e, 0);
        }
        return;
    }

    // ---- k1 GEMM role
    const int rb = blockIdx.x;   // 0..1249
    const int wave = tid >> 6, lane = tid & 63;
    const int quad = lane >> 4, l16 = lane & 15;
    _Float16* Xs = (_Float16*)smem;
    _Float16* T  = (_Float16*)smem;

    f32x4 acc[2][2][4];  // [cb][ft][nt]
#pragma unroll
    for (int c = 0; c < 2; c++)
#pragma unroll
        for (int i = 0; i < 2; i++)
#pragma unroll
            for (int j = 0; j < 4; j++) acc[c][i][j] = (f32x4){0.f, 0.f, 0.f, 0.f};

    const int row_base = rb * 64;
    const int sr = tid >> 3;          // 0..31: staged row (and sr+32)
    const int sc = (tid & 7) * 4;     // 4-float (16B) column group within 32-float chunk

    const float* xsrc  = &X[(size_t)(row_base + sr) * 256 + sc];
    const float* xsrc2 = xsrc + 32 * 256;
    const __half* wbase = &Wt[((size_t)(wave * 32 + l16)) * 256 + quad * 8];

    float4 xa, xb;
    v8h wcur[2][2], wnxt[2][2];

    // prologue: chunk 0
    xa = *(const float4*)(xsrc);
    xb = *(const float4*)(xsrc2);
#pragma unroll
    for (int cb = 0; cb < 2; cb++)
#pragma unroll
        for (int ft = 0; ft < 2; ft++)
            wcur[cb][ft] = *(const v8h*)(wbase + (size_t)(cb * 128 + ft * 16) * 256);
    {
        v4h pa = {(_Float16)xa.x, (_Float16)xa.y, (_Float16)xa.z, (_Float16)xa.w};
        v4h pb = {(_Float16)xb.x, (_Float16)xb.y, (_Float16)xb.z, (_Float16)xb.w};
        *(v4h*)&Xs[sr * 40 + sc] = pa;
        *(v4h*)&Xs[(sr + 32) * 40 + sc] = pb;
    }
    __syncthreads();

    for (int kc = 0; kc < 8; ++kc) {
        const int cur = kc & 1;
        if (kc < 7) {  // issue next-chunk loads BEFORE the MFMA block
            xa = *(const float4*)(xsrc + (kc + 1) * 32);
            xb = *(const float4*)(xsrc2 + (kc + 1) * 32);
#pragma unroll
            for (int cb = 0; cb < 2; cb++)
#pragma unroll
                for (int ft = 0; ft < 2; ft++)
                    wnxt[cb][ft] = *(const v8h*)(wbase + (size_t)(cb * 128 + ft * 16) * 256 + (kc + 1) * 32);
        }
#pragma unroll
        for (int nt = 0; nt < 4; ++nt) {
            v8h xf = *(v8h*)&Xs[cur * (64 * 40) + (nt * 16 + l16) * 40 + quad * 8];
            acc[0][0][nt] = __builtin_amdgcn_mfma_f32_16x16x32_f16(wcur[0][0], xf, acc[0][0][nt], 0, 0, 0);
            acc[0][1][nt] = __builtin_amdgcn_mfma_f32_16x16x32_f16(wcur[0][1], xf, acc[0][1][nt], 0, 0, 0);
            acc[1][0][nt] = __builtin_amdgcn_mfma_f32_16x16x32_f16(wcur[1][0], xf, acc[1][0][nt], 0, 0, 0);
            acc[1][1][nt] = __builtin_amdgcn_mfma_f32_16x16x32_f16(wcur[1][1], xf, acc[1][1][nt], 0, 0, 0);
        }
        if (kc < 7) {  // convert + store to the OTHER buffer
            const int nb = (cur ^ 1) * (64 * 40);
            v4h pa = {(_Float16)xa.x, (_Float16)xa.y, (_Float16)xa.z, (_Float16)xa.w};
            v4h pb = {(_Float16)xb.x, (_Float16)xb.y, (_Float16)xb.z, (_Float16)xb.w};
            *(v4h*)&Xs[nb + sr * 40 + sc] = pa;
            *(v4h*)&Xs[nb + (sr + 32) * 40 + sc] = pb;
#pragma unroll
            for (int cb = 0; cb < 2; cb++)
#pragma unroll
                for (int ft = 0; ft < 2; ft++)
                    wcur[cb][ft] = wnxt[cb][ft];
        }
        __syncthreads();
    }

    // ---- epilogue: LDS transpose -> coalesced 16B/lane stores into [b][n][128] ----
#pragma unroll
    for (int cb = 0; cb < 2; ++cb) {
        if (cb) __syncthreads();   // cb0 LDS reads done before overwrite
#pragma unroll
        for (int nt = 0; nt < 4; ++nt)
#pragma unroll
            for (int ft = 0; ft < 2; ++ft) {
                f32x4 a = acc[cb][ft][nt];
                v4h h = {(_Float16)a.x, (_Float16)a.y, (_Float16)a.z, (_Float16)a.w};
                *(v4h*)&T[(nt * 16 + l16) * 136 + wave * 32 + ft * 16 + quad * 4] = h;
            }
        __syncthreads();
        __half* outp = cb ? pd : ps;
#pragma unroll
        for (int pass = 0; pass < 4; ++pass) {
            const int r = pass * 16 + (tid >> 4);   // 0..63
            const int f8 = (tid & 15) * 8;          // half offset, 16B chunks
            const int R = row_base + r;
            const int b = R / N_;
            const int n = R - b * N_;
            *(float4*)(outp + ((size_t)b * N_ + n) * 128 + f8) =
                *(const float4*)&T[r * 136 + f8];
        }
    }
}

// ---------------------------------------------------------------- K2: edge scores, batch-per-XCD, 128 edges/block (4x MLP) -> scS[b][pos]
__global__ __launch_bounds__(256) void k2_scores(const __half* __restrict__ ps,
                                                 const __half* __restrict__ pd,
                                                 const int4* __restrict__ esort,
                                                 const __half* __restrict__ b1h,
                                                 const __half* __restrict__ w2h,
                                                 const float* __restrict__ b2,
                                                 const float* __restrict__ eattr,
                                                 float* __restrict__ scS) {
    const int tid = threadIdx.x;
    const int wave = tid >> 6;
    const int lane = tid & 63;
    const int bid = blockIdx.x;       // 0..9999
    const int batch = bid & 7;        // XCD-affine round-robin heuristic
    const int e0 = (bid >> 3) * 128;  // 128 edges per block

    const int hi = (lane & 7) * 16;

    v2h b1p[8], w2p[8];
    {
        const v2h* bp = (const v2h*)(b1h + hi);
        const v2h* wp = (const v2h*)(w2h + hi);
#pragma unroll
        for (int j = 0; j < 8; j++) { b1p[j] = bp[j]; w2p[j] = wp[j]; }
    }
    const float bias2 = b2[0];
    const v2h slp = {(_Float16)SLOPE, (_Float16)SLOPE};

    const __half* psb = ps + (size_t)batch * N_ * 128;
    const __half* pdb = pd + (size_t)batch * N_ * 128;
    float* scb = scS + (size_t)batch * E_;

    // hoist the 4 independent esort reads, then issue all 16 gathers before compute
    int4 er[4];
#pragma unroll
    for (int q = 0; q < 4; q++)
        er[q] = esort[e0 + wave * 32 + q * 8 + (lane >> 3)];

    float4 rs[4][2], rd[4][2];
#pragma unroll
    for (int q = 0; q < 4; q++) {
        const float4* aps = (const float4*)&psb[(size_t)er[q].x * 128 + hi];
        const float4* apd = (const float4*)&pdb[(size_t)er[q].y * 128 + hi];
        rs[q][0] = aps[0]; rs[q][1] = aps[1];
        rd[q][0] = apd[0]; rd[q][1] = apd[1];
    }

#pragma unroll
    for (int q = 0; q < 4; q++) {
        const v2h* sv = (const v2h*)rs[q];
        const v2h* dv = (const v2h*)rd[q];
        float acc = 0.f;
#pragma unroll
        for (int j = 0; j < 8; j++) {
            v2h x = sv[j] + dv[j] + b1p[j];
            v2h l = __builtin_elementwise_max(x, x * slp);   // LeakyReLU, slope<1
            acc = dot2f(l, w2p[j], acc);
        }
        acc += __shfl_xor(acc, 1);
        acc += __shfl_xor(acc, 2);
        acc += __shfl_xor(acc, 4);

        if ((lane & 7) == 0) {
            const int e = e0 + wave * 32 + q * 8 + (lane >> 3);
            scb[e] = (acc + bias2) * eattr[er[q].z];
        }
    }
}

// ---------------------------------------------------------------- K3s: per-chunk per-batch (max, shifted exp-sum); scS[b][pos]
__global__ __launch_bounds__(256) void k3s_stats(const float* __restrict__ scS,
                                                 float* __restrict__ pmax,
                                                 double* __restrict__ psum) {
    const int tid = threadIdx.x;
    const int wave = tid >> 6, lane = tid & 63;
    const int base = blockIdx.x * SEB_;

    float fm[8];
#pragma unroll
    for (int j = 0; j < 8; j++) fm[j] = -3.4e38f;
    for (int i = tid; i < SEB_; i += 256) {
        const int p = base + i;
#pragma unroll
        for (int j = 0; j < 8; j++)
            fm[j] = fmaxf(fm[j], scS[(size_t)j * E_ + p]);
    }
#pragma unroll
    for (int k = 1; k <= 32; k <<= 1)
#pragma unroll
        for (int j = 0; j < 8; j++) fm[j] = fmaxf(fm[j], __shfl_xor(fm[j], k));
    __shared__ float lmax[4][8];
    if (lane == 0)
#pragma unroll
        for (int j = 0; j < 8; j++) lmax[wave][j] = fm[j];
    __syncthreads();
    float m[8];
#pragma unroll
    for (int j = 0; j < 8; j++)
        m[j] = fmaxf(fmaxf(lmax[0][j], lmax[1][j]), fmaxf(lmax[2][j], lmax[3][j]));

    double s[8];
#pragma unroll
    for (int j = 0; j < 8; j++) s[j] = 0.0;
    for (int i = tid; i < SEB_; i += 256) {
        const int p = base + i;
#pragma unroll
        for (int j = 0; j < 8; j++)
            s[j] += (double)expf(scS[(size_t)j * E_ + p] - m[j]);
    }
#pragma unroll
    for (int k = 1; k <= 32; k <<= 1)
#pragma unroll
        for (int j = 0; j < 8; j++) s[j] += __shfl_xor(s[j], k);
    __shared__ double lsum[4][8];
    if (lane == 0)
#pragma unroll
        for (int j = 0; j < 8; j++) lsum[wave][j] = s[j];
    __syncthreads();
    if (tid < 8) {
        pmax[blockIdx.x * 8 + tid] = m[tid];
        psum[blockIdx.x * 8 + tid] = lsum[0][tid] + lsum[1][tid] + lsum[2][tid] + lsum[3][tid];
    }
}

// stats prologue: reduce SB_ chunk (m_c,l_c) -> shared m[8], inv[8]. Call from wave 0.
static __device__ __forceinline__ void stats_combine(const float* __restrict__ pmax,
                                                     const double* __restrict__ psum,
                                                     int tid, float* smx, float* sinvx) {
    if (tid < 64) {
        float mc[SB_ / 64][8];
        float v[8];
#pragma unroll
        for (int j = 0; j < 8; j++) v[j] = -3.4e38f;
#pragma unroll
        for (int g = 0; g < SB_ / 64; g++) {
            const float4* p4 = (const float4*)&pmax[(g * 64 + tid) * 8];
            float4 a = p4[0], b = p4[1];
            mc[g][0] = a.x; mc[g][1] = a.y; mc[g][2] = a.z; mc[g][3] = a.w;
            mc[g][4] = b.x; mc[g][5] = b.y; mc[g][6] = b.z; mc[g][7] = b.w;
#pragma unroll
            for (int j = 0; j < 8; j++) v[j] = fmaxf(v[j], mc[g][j]);
        }
#pragma unroll
        for (int k = 1; k <= 32; k <<= 1)
#pragma unroll
            for (int j = 0; j < 8; j++) v[j] = fmaxf(v[j], __shfl_xor(v[j], k));
        // v = global max (all lanes). Z = sum l_c * exp(m_c - m)
        double z[8];
#pragma unroll
        for (int j = 0; j < 8; j++) z[j] = 0.0;
#pragma unroll
        for (int g = 0; g < SB_ / 64; g++)
#pragma unroll
            for (int j = 0; j < 8; j++)
                z[j] += psum[(g * 64 + tid) * 8 + j] * (double)expf(mc[g][j] - v[j]);
#pragma unroll
        for (int k = 1; k <= 32; k <<= 1)
#pragma unroll
            for (int j = 0; j < 8; j++) z[j] += __shfl_xor(z[j], k);
        if (tid == 0)
#pragma unroll
            for (int j = 0; j < 8; j++) { smx[j] = v[j]; sinvx[j] = (float)(1.0 / z[j]); }
    }
}

// ---------------------------------------------------------------- K3ef: bin (128 blocks) || normalize (625 blocks, sorted->scatter-write); scS[b][pos]
__global__ __launch_bounds__(256) void k3ef(const int4* __restrict__ esort,
                                            const float* __restrict__ scS,
                                            const unsigned char* __restrict__ cmT,
                                            const float* __restrict__ pmax,
                                            const double* __restrict__ psum,
                                            const int* __restrict__ bstart,
                                            float* __restrict__ Wpf,
                                            float* __restrict__ Wpm,
                                            float* __restrict__ wout) {
    const int tid = threadIdx.x;
    __shared__ float smx[8], sinvx[8];
    __shared__ float lWf[NPB_ * 8];   // 20 KB
    __shared__ float lWm[NPB_ * 8];   // 20 KB

    stats_combine(pmax, psum, tid, smx, sinvx);

    if (blockIdx.x >= 16 * SUBS_) {   // ---- k3e role: normalize from sorted pos, scatter-write wout
        __syncthreads();
        const int p = (blockIdx.x - 16 * SUBS_) * 256 + tid;
        const int orig = esort[p].z;     // coalesced 16B read
#pragma unroll
        for (int j = 0; j < 8; j++) {
            const float v = scS[(size_t)j * E_ + p];               // coalesced read
            wout[(size_t)j * E_ + orig] = expf(v - smx[j]) * sinvx[j];  // scatter write (no stall)
        }
        return;
    }

    // ---- k3f role: bucket-aligned node-weight binning
    const int bucket = blockIdx.x / SUBS_;  // 0..15
    const int sub = blockIdx.x % SUBS_;     // 0..SUBS_-1

    for (int i = tid; i < NPB_ * 8; i += 256) { lWf[i] = 0.f; lWm[i] = 0.f; }
    __syncthreads();

    float m[8], inv[8];
#pragma unroll
    for (int j = 0; j < 8; j++) { m[j] = smx[j]; inv[j] = sinvx[j]; }

    const int bs = bstart[bucket], be = bstart[bucket + 1];
    const int len = be - bs;
    const int s0 = bs + (int)((long long)len * sub / SUBS_);
    const int s1 = bs + (int)((long long)len * (sub + 1) / SUBS_);
    const int nbase = bucket * NPB_;

    for (int p = s0 + tid; p < s1; p += 256) {
        const int4 er = esort[p];
        const int src = er.x;
        const int rel = er.y - nbase;
        float wv[8];
#pragma unroll
        for (int j = 0; j < 8; j++)
            wv[j] = expf(scS[(size_t)j * E_ + p] - m[j]) * inv[j];   // coalesced per j
        const unsigned long long mm = *(const unsigned long long*)&cmT[src * 8];
        float* lf = &lWf[rel * 8];
        float* lm = &lWm[rel * 8];
#pragma unroll
        for (int j = 0; j < 8; j++) {
            atomicAdd(&lf[j], wv[j]);
            if ((mm >> (8 * j)) & 1ull) atomicAdd(&lm[j], wv[j]);
        }
    }
    __syncthreads();

    float* of = Wpf + ((size_t)bucket * SUBS_ + sub) * (NPB_ * 8);
    float* om = Wpm + ((size_t)bucket * SUBS_ + sub) * (NPB_ * 8);
    for (int i = tid; i < NPB_ * 8; i += 256) { of[i] = lWf[i]; om[i] = lWm[i]; }
}

// ---------------------------------------------------------------- K3g: reduce SUBS_ sub-partials -> WfT/WmT [n][8]
__global__ __launch_bounds__(256) void k3g_reduce(const float* __restrict__ Wpf,
                                                  const float* __restrict__ Wpm,
                                                  float* __restrict__ WfT,
                                                  float* __restrict__ WmT) {
    const int i = blockIdx.x * 256 + threadIdx.x;  // < N_*8
    if (i >= N_ * 8) return;
    const int n = i >> 3, b = i & 7;
    const int bucket = n / NPB_;
    const int rel = n - bucket * NPB_;
    float sf = 0.f, sm = 0.f;
#pragma unroll
    for (int sub = 0; sub < SUBS_; sub++) {
        const size_t off = ((size_t)bucket * SUBS_ + sub) * (NPB_ * 8) + rel * 8 + b;
        sf += Wpf[off];
        sm += Wpm[off];
    }
    WfT[i] = sf;
    WmT[i] = sm;
}

// ---------------------------------------------------------------- K4b: dense weighted sum over X
__global__ __launch_bounds__(256) void k4b_wsum(const float* __restrict__ X,
                                                const float* __restrict__ WmT,
                                                const float* __restrict__ WfT,
                                                float* __restrict__ gpart) {
    const int c = blockIdx.x;
    const int b = blockIdx.y;
    const int tx = threadIdx.x & 63;
    const int ty = threadIdx.x >> 6;
    const int npc = N_ / NCHUNK;
    const int n0 = c * npc;

    const float4* X4 = (const float4*)(X + (size_t)b * N_ * 256);
    float4 am = {0.f, 0.f, 0.f, 0.f};
    float4 af = {0.f, 0.f, 0.f, 0.f};

#pragma unroll 5
    for (int n = n0 + ty; n < n0 + npc; n += 4) {
        float wm = WmT[n * 8 + b];
        float wf = WfT[n * 8 + b];
        float4 v = X4[(size_t)n * 64 + tx];
        am.x = fmaf(wm, v.x, am.x); am.y = fmaf(wm, v.y, am.y);
        am.z = fmaf(wm, v.z, am.z); am.w = fmaf(wm, v.w, am.w);
        af.x = fmaf(wf, v.x, af.x); af.y = fmaf(wf, v.y, af.y);
        af.z = fmaf(wf, v.z, af.z); af.w = fmaf(wf, v.w, af.w);
    }

    __shared__ float4 red[256];
    red[threadIdx.x] = am;
    __syncthreads();
    if (ty == 0) {
        float4 r1 = red[tx + 64], r2 = red[tx + 128], r3 = red[tx + 192];
        am.x += r1.x + r2.x + r3.x; am.y += r1.y + r2.y + r3.y;
        am.z += r1.z + r2.z + r3.z; am.w += r1.w + r2.w + r3.w;
    }
    __syncthreads();
    red[threadIdx.x] = af;
    __syncthreads();
    if (ty == 0) {
        float4 r1 = red[tx + 64], r2 = red[tx + 128], r3 = red[tx + 192];
        af.x += r1.x + r2.x + r3.x; af.y += r1.y + r2.y + r3.y;
        af.z += r1.z + r2.z + r3.z; af.w += r1.w + r2.w + r3.w;
        float4* gp4 = (float4*)gpart;
        gp4[((c * 2 + 0) * 8 + b) * 64 + tx] = am;
        gp4[((c * 2 + 1) * 8 + b) * 64 + tx] = af;
    }
}

// ---------------------------------------------------------------- K5: finalize
__global__ __launch_bounds__(256) void k5_final(const float* __restrict__ gpart,
                                                const int* __restrict__ cnti,
                                                float* __restrict__ gf) {
    const int b = blockIdx.x;
    const int d = threadIdx.x;
    float sm = 0.f, sf = 0.f;
    for (int c = 0; c < NCHUNK; c++) {
        sm += gpart[((c * 2 + 0) * 8 + b) * 256 + d];
        sf += gpart[((c * 2 + 1) * 8 + b) * 256 + d];
    }
    const float cn = (float)cnti[b];
    gf[b * 256 + d] = (cn > 0.f) ? (sm / cn) : (sf / (float)N_);
}

// ---------------------------------------------------------------- launch
static inline char* align16(char* p) {
    return (char*)(((uintptr_t)p + 15) & ~(uintptr_t)15);
}

extern "C" void kernel_launch(void* const* d_in, const int* in_sizes, int n_in,
                              void* d_out, int out_size, void* d_ws, size_t ws_size,
                              hipStream_t stream) {
    const float* X     = (const float*)d_in[0];
    const float* eattr = (const float*)d_in[1];
    const float* W1    = (const float*)d_in[2];
    const float* b1    = (const float*)d_in[3];
    const float* W2    = (const float*)d_in[4];
    const float* b2    = (const float*)d_in[5];
    const int*   eidx_raw = (const int*)d_in[6];
    const unsigned char* mask8 = (const unsigned char*)d_in[7];
    const unsigned int*  mask32 = (const unsigned int*)d_in[7];

    float* out  = (float*)d_out;
    float* gf   = out;          // [B,D]
    float* wout = out + 2048;   // [B,E]

    // persistent region
    char* cur = (char*)d_ws;
    __half* ps_h = (__half*)cur;             cur += (size_t)N_ * 8 * 128 * 2;   // 20.48 MB  [b][n][128]
    __half* pd_h = (__half*)cur;             cur += (size_t)N_ * 8 * 128 * 2;
    __half* Wt   = (__half*)cur;             cur += 2 * 128 * 256 * 2;
    unsigned char* cmT = (unsigned char*)cur; cur += N_ * 8;
    cur = align16(cur);
    int* cnti    = (int*)cur;                cur += 8 * 4;
    cur = align16(cur);
    float* pmax  = (float*)cur;              cur += SB_ * 8 * 4;
    cur = align16(cur);
    double* psum = (double*)cur;             cur += SB_ * 8 * 8;
    float* gpart = (float*)cur;              cur += NCHUNK * 2 * 8 * 256 * 4;
    int* hpart   = (int*)cur;                cur += NB_ * BINS_ * 4;
    int* offsetG = (int*)cur;                cur += NB_ * BINS_ * 4;
    int* bstart  = (int*)cur;                cur += 32 * 4;
    cur = align16(cur);
    int4* esort  = (int4*)cur;               cur += (size_t)E_ * 16;
    __half* b1h  = (__half*)cur;             cur += 128 * 2;
    __half* w2h  = (__half*)cur;             cur += 128 * 2;
    cur = align16(cur);
    float* scS   = (float*)cur;              cur += (size_t)E_ * 8 * 4;   // [b][pos]

    // overlay region (reuses ps_h: dead after k2/k3s... used only by k3ef/k3g/k4b)
    char* ocur = (char*)d_ws;
    float* Wpf = (float*)ocur;               ocur += (size_t)16 * SUBS_ * NPB_ * 8 * 4;  // 2.56 MB
    float* Wpm = (float*)ocur;               ocur += (size_t)16 * SUBS_ * NPB_ * 8 * 4;
    float* WfT = (float*)ocur;               ocur += N_ * 8 * 4;
    float* WmT = (float*)ocur;               ocur += N_ * 8 * 4;

    hipLaunchKernelGGL(kprep, dim3(CANONB_ + NB_ + 8), dim3(256), 0, stream,
                       eidx_raw, mask8, mask32, W1, b1, W2,
                       cmT, Wt, b1h, w2h, cnti, hpart);
    hipLaunchKernelGGL(kprefix, dim3(1), dim3(256), 0, stream, hpart, offsetG, bstart);
    hipLaunchKernelGGL(k1_mfma, dim3(1250 + NB_), dim3(256), 0, stream,
                       X, Wt, ps_h, pd_h, eidx_raw, mask32, offsetG, esort);
    hipLaunchKernelGGL(k2_scores, dim3(E_ / 16), dim3(256), 0, stream,
                       ps_h, pd_h, esort, b1h, w2h, b2, eattr, scS);
    hipLaunchKernelGGL(k3s_stats, dim3(SB_), dim3(256), 0, stream, scS, pmax, psum);
    hipLaunchKernelGGL(k3ef, dim3(16 * SUBS_ + E_ / 256), dim3(256), 0, stream,
                       esort, scS, cmT, pmax, psum, bstart, Wpf, Wpm, wout);
    hipLaunchKernelGGL(k3g_reduce, dim3((N_ * 8 + 255) / 256), dim3(256), 0, stream,
                       Wpf, Wpm, WfT, WmT);
    hipLaunchKernelGGL(k4b_wsum, dim3(NCHUNK, 8), dim3(256), 0, stream, X, WmT, WfT, gpart);
    hipLaunchKernelGGL(k5_final, dim3(8), dim3(256), 0, stream, gpart, cnti, gf);
}

// Round 12
// 276.691 us; speedup vs baseline: 1.0170x; 1.0170x over previous
//
#include <hip/hip_runtime.h>
#include <hip/hip_bf16.h>
#include <hip/hip_fp16.h>

#define B_ 8
#define N_ 10000
#define E_ 160000
#define D_ 256
#define H_ 128
#define SLOPE 0.2f
#define NCHUNK 100  // node chunks for dense weighted sum (100 nodes/chunk, 800 blocks)

// edge-sort config
#define NB_ 64            // histogram/scatter blocks
#define EPB_ (E_ / NB_)   // 2500 edges per block
#define BINS_ 256         // 16 dst-buckets x 16 src-buckets
#define NPB_ (N_ / 16)    // 625 nodes per bucket
#define SUBS_ 8           // k3f sub-splits per bucket
#define CANONB_ 313       // kprep canon blocks (covers B_*N_=80000)

// softmax stats config
#define SB_ 256           // stat blocks
#define SEB_ (E_ / SB_)   // 625 edges per stat block

typedef __attribute__((ext_vector_type(8))) _Float16 v8h;
typedef __attribute__((ext_vector_type(4))) _Float16 v4h;
typedef __attribute__((ext_vector_type(2))) _Float16 v2h;
typedef __attribute__((ext_vector_type(4))) float f32x4;

static __device__ __forceinline__ float dot2f(v2h a, v2h b, float c) {
#if __has_builtin(__builtin_amdgcn_fdot2)
    return __builtin_amdgcn_fdot2(a, b, c, false);
#else
    return fmaf((float)a.y, (float)b.y, fmaf((float)a.x, (float)b.x, c));
#endif
}

// per-block input-format detect (wave 0 ballots, LDS broadcast). sfl[0]=f_e, sfl[1]=f_m.
static __device__ __forceinline__ void block_flags(const int* __restrict__ eidx_raw,
                                                   const unsigned int* __restrict__ mask32,
                                                   int tid, int* sfl) {
    if (tid < 64) {
        unsigned long long oddnz = __ballot(eidx_raw[2 * tid + 1] != 0);
        unsigned long long mgt1  = __ballot(mask32[tid] > 1u);
        if (tid == 0) {
            sfl[0] = (oddnz == 0ull) ? 1 : 0;  // edge_index is int64
            sfl[1] = (mgt1 != 0ull) ? 1 : 0;   // mask is 1-byte bool
        }
    }
    __syncthreads();
}

// ---------------------------------------------------------------- kprep: canon (313) || hist-from-raw (64) || mask count (8)
__global__ __launch_bounds__(256) void kprep(const int* __restrict__ eidx_raw,
                                             const unsigned char* __restrict__ mask8,
                                             const unsigned int* __restrict__ mask32,
                                             const float* __restrict__ W1,
                                             const float* __restrict__ b1,
                                             const float* __restrict__ W2,
                                             unsigned char* __restrict__ cmT,
                                             __half* __restrict__ Wt,
                                             __half* __restrict__ b1h,
                                             __half* __restrict__ w2h,
                                             int* __restrict__ cnti,
                                             int* __restrict__ hpart) {
    const int tid = threadIdx.x;
    __shared__ int sfl[2];

    if (blockIdx.x < CANONB_) {  // ---- canon role: mask transpose + weight conversion
        block_flags(eidx_raw, mask32, tid, sfl);   // has __syncthreads
        const int f_m = sfl[1];
        const int i = blockIdx.x * 256 + tid;
        if (i < B_ * N_) {
            unsigned char v = f_m ? (unsigned char)(mask8[i] != 0)
                                  : (unsigned char)(mask32[i] != 0u);
            const int b = i / N_;
            const int n = i - b * N_;
            cmT[n * 8 + b] = v;
        }
        if (i < 2 * 256 * 128) {  // W1 -> fp16 transposed
            const int f = i & 127;
            const int row = i >> 7;       // 0..511
            const int c = row >> 8, k = row & 255;
            Wt[((c * 128 + f) * 256) + k] = __float2half(W1[row * 128 + f]);
        }
        if (i < 128) {
            b1h[i] = __float2half(b1[i]);
            w2h[i] = __float2half(W2[i]);
        }
    } else if (blockIdx.x < CANONB_ + NB_) {  // ---- hist role (reads raw edges, inline detect)
        block_flags(eidx_raw, mask32, tid, sfl);
        const int f_e = sfl[0];
        __shared__ int h[BINS_];
        h[tid] = 0;
        __syncthreads();
        const int hb = blockIdx.x - CANONB_;
        const int base = hb * EPB_;
        for (int i = tid; i < EPB_; i += 256) {
            const int e = base + i;
            const int s = f_e ? eidx_raw[2 * e] : eidx_raw[e];
            const int d = f_e ? eidx_raw[2 * (E_ + e)] : eidx_raw[E_ + e];
            const int bin = (d / NPB_) * 16 + s / NPB_;
            atomicAdd(&h[bin], 1);
        }
        __syncthreads();
        hpart[hb * BINS_ + tid] = h[tid];
    } else {                     // ---- mask count role (8 blocks, one per batch)
        block_flags(eidx_raw, mask32, tid, sfl);
        const int f_m = sfl[1];
        const int b = blockIdx.x - CANONB_ - NB_;
        int c = 0;
        for (int i = tid; i < N_; i += 256) {
            const int gi = b * N_ + i;
            c += (f_m ? (mask8[gi] != 0) : (mask32[gi] != 0u)) ? 1 : 0;
        }
        __shared__ int red[256];
        red[tid] = c;
        __syncthreads();
        for (int s = 128; s > 0; s >>= 1) {
            if (tid < s) red[tid] += red[tid + s];
            __syncthreads();
        }
        if (tid == 0) cnti[b] = red[0];
    }
}

// ---------------------------------------------------------------- edge sort: prefix (+ bucket starts)
__global__ __launch_bounds__(256) void kprefix(const int* __restrict__ hpart,
                                               int* __restrict__ offsetG,
                                               int* __restrict__ bstart) {
    __shared__ int cnt[BINS_];
    __shared__ int excl[BINS_];
    const int bin = threadIdx.x;
    int c = 0;
    for (int b = 0; b < NB_; b++) c += hpart[b * BINS_ + bin];
    cnt[bin] = c;
    __syncthreads();
    if (bin == 0) {
        int r = 0;
        for (int i = 0; i < BINS_; i++) { excl[i] = r; r += cnt[i]; }
    }
    __syncthreads();
    if ((bin & 15) == 0) bstart[bin >> 4] = excl[bin];
    if (bin == 0) bstart[16] = E_;
    int run = excl[bin];
    for (int b = 0; b < NB_; b++) {
        offsetG[b * BINS_ + bin] = run;
        run += hpart[b * BINS_ + bin];
    }
}

// ---------------------------------------------------------------- MEGA: k1 MFMA GEMM (1250 blocks) || scatter (64 blocks, raw edges)
// ps/pd layout: [b][n][128] fp16
__global__ __launch_bounds__(256) void k1_mfma(const float* __restrict__ X,
                                               const __half* __restrict__ Wt,
                                               __half* __restrict__ ps,
                                               __half* __restrict__ pd,
                                               const int* __restrict__ eidx_raw,
                                               const unsigned int* __restrict__ mask32,
                                               const int* __restrict__ offsetG,
                                               int4* __restrict__ esort,
                                               int* __restrict__ rank) {
    const int tid = threadIdx.x;
    // union: staging dbuf Xs[2][64*40] (10240B) | epilogue tile T[64][136] (17408B) | scatter loc[256]
    __shared__ __align__(16) char smem[64 * 136 * 2];

    if (blockIdx.x >= 1250) {  // ---- scatter role (inline format detect, no ce)
        __shared__ int sfl[2];
        block_flags(eidx_raw, mask32, tid, sfl);
        const int f_e = sfl[0];
        int* loc = (int*)smem;
        const int sb = blockIdx.x - 1250;
        loc[tid] = offsetG[sb * BINS_ + tid];
        __syncthreads();
        const int base = sb * EPB_;
        for (int i = tid; i < EPB_; i += 256) {
            const int e = base + i;
            const int s = f_e ? eidx_raw[2 * e] : eidx_raw[e];
            const int d = f_e ? eidx_raw[2 * (E_ + e)] : eidx_raw[E_ + e];
            const int bin = (d / NPB_) * 16 + s / NPB_;
            const int pos = atomicAdd(&loc[bin], 1);
            esort[pos] = make_int4(s, d, e, 0);
            rank[e] = pos;
        }
        return;
    }

    // ---- k1 GEMM role
    const int rb = blockIdx.x;   // 0..1249
    const int wave = tid >> 6, lane = tid & 63;
    const int quad = lane >> 4, l16 = lane & 15;
    _Float16* Xs = (_Float16*)smem;
    _Float16* T  = (_Float16*)smem;

    f32x4 acc[2][2][4];  // [cb][ft][nt]
#pragma unroll
    for (int c = 0; c < 2; c++)
#pragma unroll
        for (int i = 0; i < 2; i++)
#pragma unroll
            for (int j = 0; j < 4; j++) acc[c][i][j] = (f32x4){0.f, 0.f, 0.f, 0.f};

    const int row_base = rb * 64;
    const int sr = tid >> 3;          // 0..31: staged row (and sr+32)
    const int sc = (tid & 7) * 4;     // 4-float (16B) column group within 32-float chunk

    const float* xsrc  = &X[(size_t)(row_base + sr) * 256 + sc];
    const float* xsrc2 = xsrc + 32 * 256;
    const __half* wbase = &Wt[((size_t)(wave * 32 + l16)) * 256 + quad * 8];

    float4 xa, xb;
    v8h wcur[2][2], wnxt[2][2];

    // prologue: chunk 0
    xa = *(const float4*)(xsrc);
    xb = *(const float4*)(xsrc2);
#pragma unroll
    for (int cb = 0; cb < 2; cb++)
#pragma unroll
        for (int ft = 0; ft < 2; ft++)
            wcur[cb][ft] = *(const v8h*)(wbase + (size_t)(cb * 128 + ft * 16) * 256);
    {
        v4h pa = {(_Float16)xa.x, (_Float16)xa.y, (_Float16)xa.z, (_Float16)xa.w};
        v4h pb = {(_Float16)xb.x, (_Float16)xb.y, (_Float16)xb.z, (_Float16)xb.w};
        *(v4h*)&Xs[sr * 40 + sc] = pa;
        *(v4h*)&Xs[(sr + 32) * 40 + sc] = pb;
    }
    __syncthreads();

    for (int kc = 0; kc < 8; ++kc) {
        const int cur = kc & 1;
        if (kc < 7) {  // issue next-chunk loads BEFORE the MFMA block
            xa = *(const float4*)(xsrc + (kc + 1) * 32);
            xb = *(const float4*)(xsrc2 + (kc + 1) * 32);
#pragma unroll
            for (int cb = 0; cb < 2; cb++)
#pragma unroll
                for (int ft = 0; ft < 2; ft++)
                    wnxt[cb][ft] = *(const v8h*)(wbase + (size_t)(cb * 128 + ft * 16) * 256 + (kc + 1) * 32);
        }
#pragma unroll
        for (int nt = 0; nt < 4; ++nt) {
            v8h xf = *(v8h*)&Xs[cur * (64 * 40) + (nt * 16 + l16) * 40 + quad * 8];
            acc[0][0][nt] = __builtin_amdgcn_mfma_f32_16x16x32_f16(wcur[0][0], xf, acc[0][0][nt], 0, 0, 0);
            acc[0][1][nt] = __builtin_amdgcn_mfma_f32_16x16x32_f16(wcur[0][1], xf, acc[0][1][nt], 0, 0, 0);
            acc[1][0][nt] = __builtin_amdgcn_mfma_f32_16x16x32_f16(wcur[1][0], xf, acc[1][0][nt], 0, 0, 0);
            acc[1][1][nt] = __builtin_amdgcn_mfma_f32_16x16x32_f16(wcur[1][1], xf, acc[1][1][nt], 0, 0, 0);
        }
        if (kc < 7) {  // convert + store to the OTHER buffer
            const int nb = (cur ^ 1) * (64 * 40);
            v4h pa = {(_Float16)xa.x, (_Float16)xa.y, (_Float16)xa.z, (_Float16)xa.w};
            v4h pb = {(_Float16)xb.x, (_Float16)xb.y, (_Float16)xb.z, (_Float16)xb.w};
            *(v4h*)&Xs[nb + sr * 40 + sc] = pa;
            *(v4h*)&Xs[nb + (sr + 32) * 40 + sc] = pb;
#pragma unroll
            for (int cb = 0; cb < 2; cb++)
#pragma unroll
                for (int ft = 0; ft < 2; ft++)
                    wcur[cb][ft] = wnxt[cb][ft];
        }
        __syncthreads();
    }

    // ---- epilogue: LDS transpose -> coalesced 16B/lane stores into [b][n][128] ----
#pragma unroll
    for (int cb = 0; cb < 2; ++cb) {
        if (cb) __syncthreads();   // cb0 LDS reads done before overwrite
#pragma unroll
        for (int nt = 0; nt < 4; ++nt)
#pragma unroll
            for (int ft = 0; ft < 2; ++ft) {
                f32x4 a = acc[cb][ft][nt];
                v4h h = {(_Float16)a.x, (_Float16)a.y, (_Float16)a.z, (_Float16)a.w};
                *(v4h*)&T[(nt * 16 + l16) * 136 + wave * 32 + ft * 16 + quad * 4] = h;
            }
        __syncthreads();
        __half* outp = cb ? pd : ps;
#pragma unroll
        for (int pass = 0; pass < 4; ++pass) {
            const int r = pass * 16 + (tid >> 4);   // 0..63
            const int f8 = (tid & 15) * 8;          // half offset, 16B chunks
            const int R = row_base + r;
            const int b = R / N_;
            const int n = R - b * N_;
            *(float4*)(outp + ((size_t)b * N_ + n) * 128 + f8) =
                *(const float4*)&T[r * 136 + f8];
        }
    }
}

// ---------------------------------------------------------------- K2: edge scores, batch-per-XCD, 128 edges/block (4x MLP) -> scS[b][pos]
__global__ __launch_bounds__(256) void k2_scores(const __half* __restrict__ ps,
                                                 const __half* __restrict__ pd,
                                                 const int4* __restrict__ esort,
                                                 const __half* __restrict__ b1h,
                                                 const __half* __restrict__ w2h,
                                                 const float* __restrict__ b2,
                                                 const float* __restrict__ eattr,
                                                 float* __restrict__ scS) {
    const int tid = threadIdx.x;
    const int wave = tid >> 6;
    const int lane = tid & 63;
    const int bid = blockIdx.x;       // 0..9999
    const int batch = bid & 7;        // XCD-affine round-robin heuristic
    const int e0 = (bid >> 3) * 128;  // 128 edges per block

    const int hi = (lane & 7) * 16;

    v2h b1p[8], w2p[8];
    {
        const v2h* bp = (const v2h*)(b1h + hi);
        const v2h* wp = (const v2h*)(w2h + hi);
#pragma unroll
        for (int j = 0; j < 8; j++) { b1p[j] = bp[j]; w2p[j] = wp[j]; }
    }
    const float bias2 = b2[0];
    const v2h slp = {(_Float16)SLOPE, (_Float16)SLOPE};

    const __half* psb = ps + (size_t)batch * N_ * 128;
    const __half* pdb = pd + (size_t)batch * N_ * 128;
    float* scb = scS + (size_t)batch * E_;

    // hoist the 4 independent esort reads, then issue all 16 gathers before compute
    int4 er[4];
#pragma unroll
    for (int q = 0; q < 4; q++)
        er[q] = esort[e0 + wave * 32 + q * 8 + (lane >> 3)];

    float4 rs[4][2], rd[4][2];
#pragma unroll
    for (int q = 0; q < 4; q++) {
        const float4* aps = (const float4*)&psb[(size_t)er[q].x * 128 + hi];
        const float4* apd = (const float4*)&pdb[(size_t)er[q].y * 128 + hi];
        rs[q][0] = aps[0]; rs[q][1] = aps[1];
        rd[q][0] = apd[0]; rd[q][1] = apd[1];
    }

#pragma unroll
    for (int q = 0; q < 4; q++) {
        const v2h* sv = (const v2h*)rs[q];
        const v2h* dv = (const v2h*)rd[q];
        float acc = 0.f;
#pragma unroll
        for (int j = 0; j < 8; j++) {
            v2h x = sv[j] + dv[j] + b1p[j];
            v2h l = __builtin_elementwise_max(x, x * slp);   // LeakyReLU, slope<1
            acc = dot2f(l, w2p[j], acc);
        }
        acc += __shfl_xor(acc, 1);
        acc += __shfl_xor(acc, 2);
        acc += __shfl_xor(acc, 4);

        if ((lane & 7) == 0) {
            const int e = e0 + wave * 32 + q * 8 + (lane >> 3);
            scb[e] = (acc + bias2) * eattr[er[q].z];
        }
    }
}

// ---------------------------------------------------------------- K3s: per-chunk per-batch (max, shifted exp-sum); scS[b][pos]
__global__ __launch_bounds__(256) void k3s_stats(const float* __restrict__ scS,
                                                 float* __restrict__ pmax,
                                                 double* __restrict__ psum) {
    const int tid = threadIdx.x;
    const int wave = tid >> 6, lane = tid & 63;
    const int base = blockIdx.x * SEB_;

    float fm[8];
#pragma unroll
    for (int j = 0; j < 8; j++) fm[j] = -3.4e38f;
    for (int i = tid; i < SEB_; i += 256) {
        const int p = base + i;
#pragma unroll
        for (int j = 0; j < 8; j++)
            fm[j] = fmaxf(fm[j], scS[(size_t)j * E_ + p]);
    }
#pragma unroll
    for (int k = 1; k <= 32; k <<= 1)
#pragma unroll
        for (int j = 0; j < 8; j++) fm[j] = fmaxf(fm[j], __shfl_xor(fm[j], k));
    __shared__ float lmax[4][8];
    if (lane == 0)
#pragma unroll
        for (int j = 0; j < 8; j++) lmax[wave][j] = fm[j];
    __syncthreads();
    float m[8];
#pragma unroll
    for (int j = 0; j < 8; j++)
        m[j] = fmaxf(fmaxf(lmax[0][j], lmax[1][j]), fmaxf(lmax[2][j], lmax[3][j]));

    double s[8];
#pragma unroll
    for (int j = 0; j < 8; j++) s[j] = 0.0;
    for (int i = tid; i < SEB_; i += 256) {
        const int p = base + i;
#pragma unroll
        for (int j = 0; j < 8; j++)
            s[j] += (double)expf(scS[(size_t)j * E_ + p] - m[j]);
    }
#pragma unroll
    for (int k = 1; k <= 32; k <<= 1)
#pragma unroll
        for (int j = 0; j < 8; j++) s[j] += __shfl_xor(s[j], k);
    __shared__ double lsum[4][8];
    if (lane == 0)
#pragma unroll
        for (int j = 0; j < 8; j++) lsum[wave][j] = s[j];
    __syncthreads();
    if (tid < 8) {
        pmax[blockIdx.x * 8 + tid] = m[tid];
        psum[blockIdx.x * 8 + tid] = lsum[0][tid] + lsum[1][tid] + lsum[2][tid] + lsum[3][tid];
    }
}

// stats prologue: reduce SB_ chunk (m_c,l_c) -> shared m[8], inv[8]. Call from wave 0.
static __device__ __forceinline__ void stats_combine(const float* __restrict__ pmax,
                                                     const double* __restrict__ psum,
                                                     int tid, float* smx, float* sinvx) {
    if (tid < 64) {
        float mc[SB_ / 64][8];
        float v[8];
#pragma unroll
        for (int j = 0; j < 8; j++) v[j] = -3.4e38f;
#pragma unroll
        for (int g = 0; g < SB_ / 64; g++) {
            const float4* p4 = (const float4*)&pmax[(g * 64 + tid) * 8];
            float4 a = p4[0], b = p4[1];
            mc[g][0] = a.x; mc[g][1] = a.y; mc[g][2] = a.z; mc[g][3] = a.w;
            mc[g][4] = b.x; mc[g][5] = b.y; mc[g][6] = b.z; mc[g][7] = b.w;
#pragma unroll
            for (int j = 0; j < 8; j++) v[j] = fmaxf(v[j], mc[g][j]);
        }
#pragma unroll
        for (int k = 1; k <= 32; k <<= 1)
#pragma unroll
            for (int j = 0; j < 8; j++) v[j] = fmaxf(v[j], __shfl_xor(v[j], k));
        // v = global max (all lanes). Z = sum l_c * exp(m_c - m)
        double z[8];
#pragma unroll
        for (int j = 0; j < 8; j++) z[j] = 0.0;
#pragma unroll
        for (int g = 0; g < SB_ / 64; g++)
#pragma unroll
            for (int j = 0; j < 8; j++)
                z[j] += psum[(g * 64 + tid) * 8 + j] * (double)expf(mc[g][j] - v[j]);
#pragma unroll
        for (int k = 1; k <= 32; k <<= 1)
#pragma unroll
            for (int j = 0; j < 8; j++) z[j] += __shfl_xor(z[j], k);
        if (tid == 0)
#pragma unroll
            for (int j = 0; j < 8; j++) { smx[j] = v[j]; sinvx[j] = (float)(1.0 / z[j]); }
    }
}

// ---------------------------------------------------------------- K3ef: bin (128 blocks) || normalize (625 blocks, rank-gather); scS[b][pos]
__global__ __launch_bounds__(256) void k3ef(const int4* __restrict__ esort,
                                            const float* __restrict__ scS,
                                            const unsigned char* __restrict__ cmT,
                                            const float* __restrict__ pmax,
                                            const double* __restrict__ psum,
                                            const int* __restrict__ bstart,
                                            const int* __restrict__ rank,
                                            float* __restrict__ Wpf,
                                            float* __restrict__ Wpm,
                                            float* __restrict__ wout) {
    const int tid = threadIdx.x;
    __shared__ float smx[8], sinvx[8];
    __shared__ float lWf[NPB_ * 8];   // 20 KB
    __shared__ float lWm[NPB_ * 8];   // 20 KB

    stats_combine(pmax, psum, tid, smx, sinvx);

    if (blockIdx.x >= 16 * SUBS_) {   // ---- k3e role: gather scS (L2-resident), coalesced wout store
        __syncthreads();
        const int e = (blockIdx.x - 16 * SUBS_) * 256 + tid;
        const int p = rank[e];
#pragma unroll
        for (int j = 0; j < 8; j++) {
            const float v = scS[(size_t)j * E_ + p];
            wout[(size_t)j * E_ + e] = expf(v - smx[j]) * sinvx[j];   // coalesced store
        }
        return;
    }

    // ---- k3f role: bucket-aligned node-weight binning
    const int bucket = blockIdx.x / SUBS_;  // 0..15
    const int sub = blockIdx.x % SUBS_;     // 0..SUBS_-1

    for (int i = tid; i < NPB_ * 8; i += 256) { lWf[i] = 0.f; lWm[i] = 0.f; }
    __syncthreads();

    float m[8], inv[8];
#pragma unroll
    for (int j = 0; j < 8; j++) { m[j] = smx[j]; inv[j] = sinvx[j]; }

    const int bs = bstart[bucket], be = bstart[bucket + 1];
    const int len = be - bs;
    const int s0 = bs + (int)((long long)len * sub / SUBS_);
    const int s1 = bs + (int)((long long)len * (sub + 1) / SUBS_);
    const int nbase = bucket * NPB_;

    for (int p = s0 + tid; p < s1; p += 256) {
        const int4 er = esort[p];
        const int src = er.x;
        const int rel = er.y - nbase;
        float wv[8];
#pragma unroll
        for (int j = 0; j < 8; j++)
            wv[j] = expf(scS[(size_t)j * E_ + p] - m[j]) * inv[j];   // coalesced per j
        const unsigned long long mm = *(const unsigned long long*)&cmT[src * 8];
        float* lf = &lWf[rel * 8];
        float* lm = &lWm[rel * 8];
#pragma unroll
        for (int j = 0; j < 8; j++) {
            atomicAdd(&lf[j], wv[j]);
            if ((mm >> (8 * j)) & 1ull) atomicAdd(&lm[j], wv[j]);
        }
    }
    __syncthreads();

    float* of = Wpf + ((size_t)bucket * SUBS_ + sub) * (NPB_ * 8);
    float* om = Wpm + ((size_t)bucket * SUBS_ + sub) * (NPB_ * 8);
    for (int i = tid; i < NPB_ * 8; i += 256) { of[i] = lWf[i]; om[i] = lWm[i]; }
}

// ---------------------------------------------------------------- K3g: reduce SUBS_ sub-partials -> WfT/WmT [n][8]
__global__ __launch_bounds__(256) void k3g_reduce(const float* __restrict__ Wpf,
                                                  const float* __restrict__ Wpm,
                                                  float* __restrict__ WfT,
                                                  float* __restrict__ WmT) {
    const int i = blockIdx.x * 256 + threadIdx.x;  // < N_*8
    if (i >= N_ * 8) return;
    const int n = i >> 3, b = i & 7;
    const int bucket = n / NPB_;
    const int rel = n - bucket * NPB_;
    float sf = 0.f, sm = 0.f;
#pragma unroll
    for (int sub = 0; sub < SUBS_; sub++) {
        const size_t off = ((size_t)bucket * SUBS_ + sub) * (NPB_ * 8) + rel * 8 + b;
        sf += Wpf[off];
        sm += Wpm[off];
    }
    WfT[i] = sf;
    WmT[i] = sm;
}

// ---------------------------------------------------------------- K4b: dense weighted sum over X
__global__ __launch_bounds__(256) void k4b_wsum(const float* __restrict__ X,
                                                const float* __restrict__ WmT,
                                                const float* __restrict__ WfT,
                                                float* __restrict__ gpart) {
    const int c = blockIdx.x;
    const int b = blockIdx.y;
    const int tx = threadIdx.x & 63;
    const int ty = threadIdx.x >> 6;
    const int npc = N_ / NCHUNK;
    const int n0 = c * npc;

    const float4* X4 = (const float4*)(X + (size_t)b * N_ * 256);
    float4 am = {0.f, 0.f, 0.f, 0.f};
    float4 af = {0.f, 0.f, 0.f, 0.f};

#pragma unroll 5
    for (int n = n0 + ty; n < n0 + npc; n += 4) {
        float wm = WmT[n * 8 + b];
        float wf = WfT[n * 8 + b];
        float4 v = X4[(size_t)n * 64 + tx];
        am.x = fmaf(wm, v.x, am.x); am.y = fmaf(wm, v.y, am.y);
        am.z = fmaf(wm, v.z, am.z); am.w = fmaf(wm, v.w, am.w);
        af.x = fmaf(wf, v.x, af.x); af.y = fmaf(wf, v.y, af.y);
        af.z = fmaf(wf, v.z, af.z); af.w = fmaf(wf, v.w, af.w);
    }

    __shared__ float4 red[256];
    red[threadIdx.x] = am;
    __syncthreads();
    if (ty == 0) {
        float4 r1 = red[tx + 64], r2 = red[tx + 128], r3 = red[tx + 192];
        am.x += r1.x + r2.x + r3.x; am.y += r1.y + r2.y + r3.y;
        am.z += r1.z + r2.z + r3.z; am.w += r1.w + r2.w + r3.w;
    }
    __syncthreads();
    red[threadIdx.x] = af;
    __syncthreads();
    if (ty == 0) {
        float4 r1 = red[tx + 64], r2 = red[tx + 128], r3 = red[tx + 192];
        af.x += r1.x + r2.x + r3.x; af.y += r1.y + r2.y + r3.y;
        af.z += r1.z + r2.z + r3.z; af.w += r1.w + r2.w + r3.w;
        float4* gp4 = (float4*)gpart;
        gp4[((c * 2 + 0) * 8 + b) * 64 + tx] = am;
        gp4[((c * 2 + 1) * 8 + b) * 64 + tx] = af;
    }
}

// ---------------------------------------------------------------- K5: finalize
__global__ __launch_bounds__(256) void k5_final(const float* __restrict__ gpart,
                                                const int* __restrict__ cnti,
                                                float* __restrict__ gf) {
    const int b = blockIdx.x;
    const int d = threadIdx.x;
    float sm = 0.f, sf = 0.f;
    for (int c = 0; c < NCHUNK; c++) {
        sm += gpart[((c * 2 + 0) * 8 + b) * 256 + d];
        sf += gpart[((c * 2 + 1) * 8 + b) * 256 + d];
    }
    const float cn = (float)cnti[b];
    gf[b * 256 + d] = (cn > 0.f) ? (sm / cn) : (sf / (float)N_);
}

// ---------------------------------------------------------------- launch
static inline char* align16(char* p) {
    return (char*)(((uintptr_t)p + 15) & ~(uintptr_t)15);
}

extern "C" void kernel_launch(void* const* d_in, const int* in_sizes, int n_in,
                              void* d_out, int out_size, void* d_ws, size_t ws_size,
                              hipStream_t stream) {
    const float* X     = (const float*)d_in[0];
    const float* eattr = (const float*)d_in[1];
    const float* W1    = (const float*)d_in[2];
    const float* b1    = (const float*)d_in[3];
    const float* W2    = (const float*)d_in[4];
    const float* b2    = (const float*)d_in[5];
    const int*   eidx_raw = (const int*)d_in[6];
    const unsigned char* mask8 = (const unsigned char*)d_in[7];
    const unsigned int*  mask32 = (const unsigned int*)d_in[7];

    float* out  = (float*)d_out;
    float* gf   = out;          // [B,D]
    float* wout = out + 2048;   // [B,E]

    // persistent region
    char* cur = (char*)d_ws;
    __half* ps_h = (__half*)cur;             cur += (size_t)N_ * 8 * 128 * 2;   // 20.48 MB  [b][n][128]
    __half* pd_h = (__half*)cur;             cur += (size_t)N_ * 8 * 128 * 2;
    __half* Wt   = (__half*)cur;             cur += 2 * 128 * 256 * 2;
    unsigned char* cmT = (unsigned char*)cur; cur += N_ * 8;
    cur = align16(cur);
    int* cnti    = (int*)cur;                cur += 8 * 4;
    cur = align16(cur);
    float* pmax  = (float*)cur;              cur += SB_ * 8 * 4;
    cur = align16(cur);
    double* psum = (double*)cur;             cur += SB_ * 8 * 8;
    float* gpart = (float*)cur;              cur += NCHUNK * 2 * 8 * 256 * 4;
    int* hpart   = (int*)cur;                cur += NB_ * BINS_ * 4;
    int* offsetG = (int*)cur;                cur += NB_ * BINS_ * 4;
    int* bstart  = (int*)cur;                cur += 32 * 4;
    cur = align16(cur);
    int4* esort  = (int4*)cur;               cur += (size_t)E_ * 16;
    int* rankB   = (int*)cur;                cur += E_ * 4;
    __half* b1h  = (__half*)cur;             cur += 128 * 2;
    __half* w2h  = (__half*)cur;             cur += 128 * 2;
    cur = align16(cur);
    float* scS   = (float*)cur;              cur += (size_t)E_ * 8 * 4;   // [b][pos]

    // overlay region (reuses ps_h: dead after k2/k3s... used only by k3ef/k3g/k4b)
    char* ocur = (char*)d_ws;
    float* Wpf = (float*)ocur;               ocur += (size_t)16 * SUBS_ * NPB_ * 8 * 4;  // 2.56 MB
    float* Wpm = (float*)ocur;               ocur += (size_t)16 * SUBS_ * NPB_ * 8 * 4;
    float* WfT = (float*)ocur;               ocur += N_ * 8 * 4;
    float* WmT = (float*)ocur;               ocur += N_ * 8 * 4;

    hipLaunchKernelGGL(kprep, dim3(CANONB_ + NB_ + 8), dim3(256), 0, stream,
                       eidx_raw, mask8, mask32, W1, b1, W2,
                       cmT, Wt, b1h, w2h, cnti, hpart);
    hipLaunchKernelGGL(kprefix, dim3(1), dim3(256), 0, stream, hpart, offsetG, bstart);
    hipLaunchKernelGGL(k1_mfma, dim3(1250 + NB_), dim3(256), 0, stream,
                       X, Wt, ps_h, pd_h, eidx_raw, mask32, offsetG, esort, rankB);
    hipLaunchKernelGGL(k2_scores, dim3(E_ / 16), dim3(256), 0, stream,
                       ps_h, pd_h, esort, b1h, w2h, b2, eattr, scS);
    hipLaunchKernelGGL(k3s_stats, dim3(SB_), dim3(256), 0, stream, scS, pmax, psum);
    hipLaunchKernelGGL(k3ef, dim3(16 * SUBS_ + E_ / 256), dim3(256), 0, stream,
                       esort, scS, cmT, pmax, psum, bstart, rankB, Wpf, Wpm, wout);
    hipLaunchKernelGGL(k3g_reduce, dim3((N_ * 8 + 255) / 256), dim3(256), 0, stream,
                       Wpf, Wpm, WfT, WmT);
    hipLaunchKernelGGL(k4b_wsum, dim3(NCHUNK, 8), dim3(256), 0, stream, X, WmT, WfT, gpart);
    hipLaunchKernelGGL(k5_final, dim3(8), dim3(256), 0, stream, gpart, cnti, gf);
}

// Round 13
// 270.079 us; speedup vs baseline: 1.0419x; 1.0245x over previous
//
#include <hip/hip_runtime.h>
#include <hip/hip_bf16.h>
#include <hip/hip_fp16.h>

#define B_ 8
#define N_ 10000
#define E_ 160000
#define D_ 256
#define H_ 128
#define SLOPE 0.2f
#define NCHUNK 100  // node chunks for dense weighted sum (100 nodes/chunk, 800 blocks)

// edge-sort config
#define NB_ 64            // histogram/scatter blocks
#define EPB_ (E_ / NB_)   // 2500 edges per block
#define BINS_ 256         // 16 dst-buckets x 16 src-buckets
#define NPB_ (N_ / 16)    // 625 nodes per bucket
#define SUBS_ 8           // k3f sub-splits per bucket

// softmax stats config
#define SB_ 256           // stat blocks
#define SEB_ (E_ / SB_)   // 625 edges per stat block

typedef __attribute__((ext_vector_type(8))) _Float16 v8h;
typedef __attribute__((ext_vector_type(4))) _Float16 v4h;
typedef __attribute__((ext_vector_type(2))) _Float16 v2h;
typedef __attribute__((ext_vector_type(4))) float f32x4;

static __device__ __forceinline__ float dot2f(v2h a, v2h b, float c) {
#if __has_builtin(__builtin_amdgcn_fdot2)
    return __builtin_amdgcn_fdot2(a, b, c, false);
#else
    return fmaf((float)a.y, (float)b.y, fmaf((float)a.x, (float)b.x, c));
#endif
}

// per-block input-format detect (wave 0 ballots, LDS broadcast). sfl[0]=f_e, sfl[1]=f_m.
static __device__ __forceinline__ void block_flags(const int* __restrict__ eidx_raw,
                                                   const unsigned int* __restrict__ mask32,
                                                   int tid, int* sfl) {
    if (tid < 64) {
        unsigned long long oddnz = __ballot(eidx_raw[2 * tid + 1] != 0);
        unsigned long long mgt1  = __ballot(mask32[tid] > 1u);
        if (tid == 0) {
            sfl[0] = (oddnz == 0ull) ? 1 : 0;  // edge_index is int64
            sfl[1] = (mgt1 != 0ull) ? 1 : 0;   // mask is 1-byte bool
        }
    }
    __syncthreads();
}

// ---------------------------------------------------------------- kprep: canon (1250 blocks) || hist-from-raw (64 blocks)
__global__ __launch_bounds__(256) void kprep(const int* __restrict__ eidx_raw,
                                             const unsigned char* __restrict__ mask8,
                                             const unsigned int* __restrict__ mask32,
                                             const float* __restrict__ W1,
                                             const float* __restrict__ b1,
                                             const float* __restrict__ W2,
                                             int* __restrict__ ce,
                                             unsigned char* __restrict__ cmT,
                                             __half* __restrict__ Wt,
                                             __half* __restrict__ b1h,
                                             __half* __restrict__ w2h,
                                             int* __restrict__ cnti,
                                             int* __restrict__ hpart) {
    const int tid = threadIdx.x;
    __shared__ int sfl[2];
    __shared__ int scnt[8];

    if (blockIdx.x < 1250) {  // ---- canon role
        if (tid < 8) scnt[tid] = 0;
        block_flags(eidx_raw, mask32, tid, sfl);   // has __syncthreads
        const int f_e = sfl[0], f_m = sfl[1];
        const int i = blockIdx.x * 256 + tid;
        if (i < 2 * E_) ce[i] = f_e ? eidx_raw[2 * i] : eidx_raw[i];
        if (i < B_ * N_) {
            unsigned char v = f_m ? (unsigned char)(mask8[i] != 0)
                                  : (unsigned char)(mask32[i] != 0u);
            const int b = i / N_;
            const int n = i - b * N_;
            cmT[n * 8 + b] = v;
            if (v) atomicAdd(&scnt[b], 1);     // LDS atomic: cheap
        }
        if (i < 2 * 256 * 128) {  // W1 -> fp16 transposed
            const int f = i & 127;
            const int row = i >> 7;       // 0..511
            const int c = row >> 8, k = row & 255;
            Wt[((c * 128 + f) * 256) + k] = __float2half(W1[row * 128 + f]);
        }
        if (i < 128) {
            b1h[i] = __float2half(b1[i]);
            w2h[i] = __float2half(W2[i]);
        }
        __syncthreads();
        if (tid < 8 && scnt[tid]) atomicAdd(&cnti[tid], scnt[tid]);  // ~1 atomic/block
    } else {                   // ---- hist role (reads raw edges, inline detect)
        block_flags(eidx_raw, mask32, tid, sfl);
        const int f_e = sfl[0];
        __shared__ int h[BINS_];
        h[tid] = 0;
        __syncthreads();
        const int hb = blockIdx.x - 1250;
        const int base = hb * EPB_;
        for (int i = tid; i < EPB_; i += 256) {
            const int e = base + i;
            const int s = f_e ? eidx_raw[2 * e] : eidx_raw[e];
            const int d = f_e ? eidx_raw[2 * (E_ + e)] : eidx_raw[E_ + e];
            const int bin = (d / NPB_) * 16 + s / NPB_;
            atomicAdd(&h[bin], 1);
        }
        __syncthreads();
        hpart[hb * BINS_ + tid] = h[tid];
    }
}

// ---------------------------------------------------------------- edge sort: prefix (+ bucket starts)
__global__ __launch_bounds__(256) void kprefix(const int* __restrict__ hpart,
                                               int* __restrict__ offsetG,
                                               int* __restrict__ bstart) {
    __shared__ int cnt[BINS_];
    __shared__ int excl[BINS_];
    const int bin = threadIdx.x;
    int c = 0;
    for (int b = 0; b < NB_; b++) c += hpart[b * BINS_ + bin];
    cnt[bin] = c;
    __syncthreads();
    if (bin == 0) {
        int r = 0;
        for (int i = 0; i < BINS_; i++) { excl[i] = r; r += cnt[i]; }
    }
    __syncthreads();
    if ((bin & 15) == 0) bstart[bin >> 4] = excl[bin];
    if (bin == 0) bstart[16] = E_;
    int run = excl[bin];
    for (int b = 0; b < NB_; b++) {
        offsetG[b * BINS_ + bin] = run;
        run += hpart[b * BINS_ + bin];
    }
}

// ---------------------------------------------------------------- MEGA: k1 MFMA GEMM (1250 blocks) || scatter (64 blocks)
// ps/pd layout: [b][n][128] fp16
__global__ __launch_bounds__(256) void k1_mfma(const float* __restrict__ X,
                                               const __half* __restrict__ Wt,
                                               __half* __restrict__ ps,
                                               __half* __restrict__ pd,
                                               const int* __restrict__ ce,
                                               const int* __restrict__ offsetG,
                                               int4* __restrict__ esort,
                                               int* __restrict__ rank) {
    const int tid = threadIdx.x;
    // union: staging dbuf Xs[2][64*40] (10240B) | epilogue tile T[64][136] (17408B) | scatter loc[256]
    __shared__ __align__(16) char smem[64 * 136 * 2];

    if (blockIdx.x >= 1250) {  // ---- scatter role
        int* loc = (int*)smem;
        const int sb = blockIdx.x - 1250;
        loc[tid] = offsetG[sb * BINS_ + tid];
        __syncthreads();
        const int base = sb * EPB_;
        for (int i = tid; i < EPB_; i += 256) {
            const int e = base + i;
            const int s = ce[e], d = ce[E_ + e];
            const int bin = (d / NPB_) * 16 + s / NPB_;
            const int pos = atomicAdd(&loc[bin], 1);
            esort[pos] = make_int4(s, d, e, 0);
            rank[e] = pos;
        }
        return;
    }

    // ---- k1 GEMM role
    const int rb = blockIdx.x;   // 0..1249
    const int wave = tid >> 6, lane = tid & 63;
    const int quad = lane >> 4, l16 = lane & 15;
    _Float16* Xs = (_Float16*)smem;
    _Float16* T  = (_Float16*)smem;

    f32x4 acc[2][2][4];  // [cb][ft][nt]
#pragma unroll
    for (int c = 0; c < 2; c++)
#pragma unroll
        for (int i = 0; i < 2; i++)
#pragma unroll
            for (int j = 0; j < 4; j++) acc[c][i][j] = (f32x4){0.f, 0.f, 0.f, 0.f};

    const int row_base = rb * 64;
    const int sr = tid >> 3;          // 0..31: staged row (and sr+32)
    const int sc = (tid & 7) * 4;     // 4-float (16B) column group within 32-float chunk

    const float* xsrc  = &X[(size_t)(row_base + sr) * 256 + sc];
    const float* xsrc2 = xsrc + 32 * 256;
    const __half* wbase = &Wt[((size_t)(wave * 32 + l16)) * 256 + quad * 8];

    float4 xa, xb;
    v8h wcur[2][2], wnxt[2][2];

    // prologue: chunk 0
    xa = *(const float4*)(xsrc);
    xb = *(const float4*)(xsrc2);
#pragma unroll
    for (int cb = 0; cb < 2; cb++)
#pragma unroll
        for (int ft = 0; ft < 2; ft++)
            wcur[cb][ft] = *(const v8h*)(wbase + (size_t)(cb * 128 + ft * 16) * 256);
    {
        v4h pa = {(_Float16)xa.x, (_Float16)xa.y, (_Float16)xa.z, (_Float16)xa.w};
        v4h pb = {(_Float16)xb.x, (_Float16)xb.y, (_Float16)xb.z, (_Float16)xb.w};
        *(v4h*)&Xs[sr * 40 + sc] = pa;
        *(v4h*)&Xs[(sr + 32) * 40 + sc] = pb;
    }
    __syncthreads();

    for (int kc = 0; kc < 8; ++kc) {
        const int cur = kc & 1;
        if (kc < 7) {  // issue next-chunk loads BEFORE the MFMA block
            xa = *(const float4*)(xsrc + (kc + 1) * 32);
            xb = *(const float4*)(xsrc2 + (kc + 1) * 32);
#pragma unroll
            for (int cb = 0; cb < 2; cb++)
#pragma unroll
                for (int ft = 0; ft < 2; ft++)
                    wnxt[cb][ft] = *(const v8h*)(wbase + (size_t)(cb * 128 + ft * 16) * 256 + (kc + 1) * 32);
        }
#pragma unroll
        for (int nt = 0; nt < 4; ++nt) {
            v8h xf = *(v8h*)&Xs[cur * (64 * 40) + (nt * 16 + l16) * 40 + quad * 8];
            acc[0][0][nt] = __builtin_amdgcn_mfma_f32_16x16x32_f16(wcur[0][0], xf, acc[0][0][nt], 0, 0, 0);
            acc[0][1][nt] = __builtin_amdgcn_mfma_f32_16x16x32_f16(wcur[0][1], xf, acc[0][1][nt], 0, 0, 0);
            acc[1][0][nt] = __builtin_amdgcn_mfma_f32_16x16x32_f16(wcur[1][0], xf, acc[1][0][nt], 0, 0, 0);
            acc[1][1][nt] = __builtin_amdgcn_mfma_f32_16x16x32_f16(wcur[1][1], xf, acc[1][1][nt], 0, 0, 0);
        }
        if (kc < 7) {  // convert + store to the OTHER buffer
            const int nb = (cur ^ 1) * (64 * 40);
            v4h pa = {(_Float16)xa.x, (_Float16)xa.y, (_Float16)xa.z, (_Float16)xa.w};
            v4h pb = {(_Float16)xb.x, (_Float16)xb.y, (_Float16)xb.z, (_Float16)xb.w};
            *(v4h*)&Xs[nb + sr * 40 + sc] = pa;
            *(v4h*)&Xs[nb + (sr + 32) * 40 + sc] = pb;
#pragma unroll
            for (int cb = 0; cb < 2; cb++)
#pragma unroll
                for (int ft = 0; ft < 2; ft++)
                    wcur[cb][ft] = wnxt[cb][ft];
        }
        __syncthreads();
    }

    // ---- epilogue: LDS transpose -> coalesced 16B/lane stores into [b][n][128] ----
#pragma unroll
    for (int cb = 0; cb < 2; ++cb) {
        if (cb) __syncthreads();   // cb0 LDS reads done before overwrite
#pragma unroll
        for (int nt = 0; nt < 4; ++nt)
#pragma unroll
            for (int ft = 0; ft < 2; ++ft) {
                f32x4 a = acc[cb][ft][nt];
                v4h h = {(_Float16)a.x, (_Float16)a.y, (_Float16)a.z, (_Float16)a.w};
                *(v4h*)&T[(nt * 16 + l16) * 136 + wave * 32 + ft * 16 + quad * 4] = h;
            }
        __syncthreads();
        __half* outp = cb ? pd : ps;
#pragma unroll
        for (int pass = 0; pass < 4; ++pass) {
            const int r = pass * 16 + (tid >> 4);   // 0..63
            const int f8 = (tid & 15) * 8;          // half offset, 16B chunks
            const int R = row_base + r;
            const int b = R / N_;
            const int n = R - b * N_;
            *(float4*)(outp + ((size_t)b * N_ + n) * 128 + f8) =
                *(const float4*)&T[r * 136 + f8];
        }
    }
}

// ---------------------------------------------------------------- K2: edge scores, batch-per-XCD, 128 edges/block (4x MLP) -> scS[b][pos]
__global__ __launch_bounds__(256) void k2_scores(const __half* __restrict__ ps,
                                                 const __half* __restrict__ pd,
                                                 const int4* __restrict__ esort,
                                                 const __half* __restrict__ b1h,
                                                 const __half* __restrict__ w2h,
                                                 const float* __restrict__ b2,
                                                 const float* __restrict__ eattr,
                                                 float* __restrict__ scS) {
    const int tid = threadIdx.x;
    const int wave = tid >> 6;
    const int lane = tid & 63;
    const int bid = blockIdx.x;       // 0..9999
    const int batch = bid & 7;        // XCD-affine round-robin heuristic
    const int e0 = (bid >> 3) * 128;  // 128 edges per block

    const int hi = (lane & 7) * 16;

    v2h b1p[8], w2p[8];
    {
        const v2h* bp = (const v2h*)(b1h + hi);
        const v2h* wp = (const v2h*)(w2h + hi);
#pragma unroll
        for (int j = 0; j < 8; j++) { b1p[j] = bp[j]; w2p[j] = wp[j]; }
    }
    const float bias2 = b2[0];
    const v2h slp = {(_Float16)SLOPE, (_Float16)SLOPE};

    const __half* psb = ps + (size_t)batch * N_ * 128;
    const __half* pdb = pd + (size_t)batch * N_ * 128;
    float* scb = scS + (size_t)batch * E_;

    // hoist the 4 independent esort reads, then issue all 16 gathers before compute
    int4 er[4];
#pragma unroll
    for (int q = 0; q < 4; q++)
        er[q] = esort[e0 + wave * 32 + q * 8 + (lane >> 3)];

    float4 rs[4][2], rd[4][2];
#pragma unroll
    for (int q = 0; q < 4; q++) {
        const float4* aps = (const float4*)&psb[(size_t)er[q].x * 128 + hi];
        const float4* apd = (const float4*)&pdb[(size_t)er[q].y * 128 + hi];
        rs[q][0] = aps[0]; rs[q][1] = aps[1];
        rd[q][0] = apd[0]; rd[q][1] = apd[1];
    }

#pragma unroll
    for (int q = 0; q < 4; q++) {
        const v2h* sv = (const v2h*)rs[q];
        const v2h* dv = (const v2h*)rd[q];
        float acc = 0.f;
#pragma unroll
        for (int j = 0; j < 8; j++) {
            v2h x = sv[j] + dv[j] + b1p[j];
            v2h l = __builtin_elementwise_max(x, x * slp);   // LeakyReLU, slope<1
            acc = dot2f(l, w2p[j], acc);
        }
        acc += __shfl_xor(acc, 1);
        acc += __shfl_xor(acc, 2);
        acc += __shfl_xor(acc, 4);

        if ((lane & 7) == 0) {
            const int e = e0 + wave * 32 + q * 8 + (lane >> 3);
            scb[e] = (acc + bias2) * eattr[er[q].z];
        }
    }
}

// ---------------------------------------------------------------- K3s: per-chunk per-batch (max, shifted exp-sum); scS[b][pos]
__global__ __launch_bounds__(256) void k3s_stats(const float* __restrict__ scS,
                                                 float* __restrict__ pmax,
                                                 double* __restrict__ psum) {
    const int tid = threadIdx.x;
    const int wave = tid >> 6, lane = tid & 63;
    const int base = blockIdx.x * SEB_;

    float fm[8];
#pragma unroll
    for (int j = 0; j < 8; j++) fm[j] = -3.4e38f;
    for (int i = tid; i < SEB_; i += 256) {
        const int p = base + i;
#pragma unroll
        for (int j = 0; j < 8; j++)
            fm[j] = fmaxf(fm[j], scS[(size_t)j * E_ + p]);
    }
#pragma unroll
    for (int k = 1; k <= 32; k <<= 1)
#pragma unroll
        for (int j = 0; j < 8; j++) fm[j] = fmaxf(fm[j], __shfl_xor(fm[j], k));
    __shared__ float lmax[4][8];
    if (lane == 0)
#pragma unroll
        for (int j = 0; j < 8; j++) lmax[wave][j] = fm[j];
    __syncthreads();
    float m[8];
#pragma unroll
    for (int j = 0; j < 8; j++)
        m[j] = fmaxf(fmaxf(lmax[0][j], lmax[1][j]), fmaxf(lmax[2][j], lmax[3][j]));

    double s[8];
#pragma unroll
    for (int j = 0; j < 8; j++) s[j] = 0.0;
    for (int i = tid; i < SEB_; i += 256) {
        const int p = base + i;
#pragma unroll
        for (int j = 0; j < 8; j++)
            s[j] += (double)expf(scS[(size_t)j * E_ + p] - m[j]);
    }
#pragma unroll
    for (int k = 1; k <= 32; k <<= 1)
#pragma unroll
        for (int j = 0; j < 8; j++) s[j] += __shfl_xor(s[j], k);
    __shared__ double lsum[4][8];
    if (lane == 0)
#pragma unroll
        for (int j = 0; j < 8; j++) lsum[wave][j] = s[j];
    __syncthreads();
    if (tid < 8) {
        pmax[blockIdx.x * 8 + tid] = m[tid];
        psum[blockIdx.x * 8 + tid] = lsum[0][tid] + lsum[1][tid] + lsum[2][tid] + lsum[3][tid];
    }
}

// stats prologue: reduce SB_ chunk (m_c,l_c) -> shared m[8], inv[8]. Call from wave 0.
static __device__ __forceinline__ void stats_combine(const float* __restrict__ pmax,
                                                     const double* __restrict__ psum,
                                                     int tid, float* smx, float* sinvx) {
    if (tid < 64) {
        float mc[SB_ / 64][8];
        float v[8];
#pragma unroll
        for (int j = 0; j < 8; j++) v[j] = -3.4e38f;
#pragma unroll
        for (int g = 0; g < SB_ / 64; g++) {
            const float4* p4 = (const float4*)&pmax[(g * 64 + tid) * 8];
            float4 a = p4[0], b = p4[1];
            mc[g][0] = a.x; mc[g][1] = a.y; mc[g][2] = a.z; mc[g][3] = a.w;
            mc[g][4] = b.x; mc[g][5] = b.y; mc[g][6] = b.z; mc[g][7] = b.w;
#pragma unroll
            for (int j = 0; j < 8; j++) v[j] = fmaxf(v[j], mc[g][j]);
        }
#pragma unroll
        for (int k = 1; k <= 32; k <<= 1)
#pragma unroll
            for (int j = 0; j < 8; j++) v[j] = fmaxf(v[j], __shfl_xor(v[j], k));
        // v = global max (all lanes). Z = sum l_c * exp(m_c - m)
        double z[8];
#pragma unroll
        for (int j = 0; j < 8; j++) z[j] = 0.0;
#pragma unroll
        for (int g = 0; g < SB_ / 64; g++)
#pragma unroll
            for (int j = 0; j < 8; j++)
                z[j] += psum[(g * 64 + tid) * 8 + j] * (double)expf(mc[g][j] - v[j]);
#pragma unroll
        for (int k = 1; k <= 32; k <<= 1)
#pragma unroll
            for (int j = 0; j < 8; j++) z[j] += __shfl_xor(z[j], k);
        if (tid == 0)
#pragma unroll
            for (int j = 0; j < 8; j++) { smx[j] = v[j]; sinvx[j] = (float)(1.0 / z[j]); }
    }
}

// ---------------------------------------------------------------- K3ef: bin (128 blocks) || normalize (625 blocks); scS[b][pos]
__global__ __launch_bounds__(256) void k3ef(const int4* __restrict__ esort,
                                            const float* __restrict__ scS,
                                            const unsigned char* __restrict__ cmT,
                                            const float* __restrict__ pmax,
                                            const double* __restrict__ psum,
                                            const int* __restrict__ bstart,
                                            const int* __restrict__ rank,
                                            float* __restrict__ Wpf,
                                            float* __restrict__ Wpm,
                                            float* __restrict__ wout) {
    const int tid = threadIdx.x;
    __shared__ float smx[8], sinvx[8];
    __shared__ float lWf[NPB_ * 8];   // 20 KB
    __shared__ float lWm[NPB_ * 8];   // 20 KB

    stats_combine(pmax, psum, tid, smx, sinvx);

    if (blockIdx.x >= 16 * SUBS_) {   // ---- k3e role: normalize -> wout
        __syncthreads();
        const int e = (blockIdx.x - 16 * SUBS_) * 256 + tid;
        const int p = rank[e];
#pragma unroll
        for (int j = 0; j < 8; j++) {
            const float v = scS[(size_t)j * E_ + p];
            wout[(size_t)j * E_ + e] = expf(v - smx[j]) * sinvx[j];   // coalesced store
        }
        return;
    }

    // ---- k3f role: bucket-aligned node-weight binning
    const int bucket = blockIdx.x / SUBS_;  // 0..15
    const int sub = blockIdx.x % SUBS_;     // 0..SUBS_-1

    for (int i = tid; i < NPB_ * 8; i += 256) { lWf[i] = 0.f; lWm[i] = 0.f; }
    __syncthreads();

    float m[8], inv[8];
#pragma unroll
    for (int j = 0; j < 8; j++) { m[j] = smx[j]; inv[j] = sinvx[j]; }

    const int bs = bstart[bucket], be = bstart[bucket + 1];
    const int len = be - bs;
    const int s0 = bs + (int)((long long)len * sub / SUBS_);
    const int s1 = bs + (int)((long long)len * (sub + 1) / SUBS_);
    const int nbase = bucket * NPB_;

    for (int p = s0 + tid; p < s1; p += 256) {
        const int4 er = esort[p];
        const int src = er.x;
        const int rel = er.y - nbase;
        float wv[8];
#pragma unroll
        for (int j = 0; j < 8; j++)
            wv[j] = expf(scS[(size_t)j * E_ + p] - m[j]) * inv[j];   // coalesced per j
        const unsigned long long mm = *(const unsigned long long*)&cmT[src * 8];
        float* lf = &lWf[rel * 8];
        float* lm = &lWm[rel * 8];
#pragma unroll
        for (int j = 0; j < 8; j++) {
            atomicAdd(&lf[j], wv[j]);
            if ((mm >> (8 * j)) & 1ull) atomicAdd(&lm[j], wv[j]);
        }
    }
    __syncthreads();

    float* of = Wpf + ((size_t)bucket * SUBS_ + sub) * (NPB_ * 8);
    float* om = Wpm + ((size_t)bucket * SUBS_ + sub) * (NPB_ * 8);
    for (int i = tid; i < NPB_ * 8; i += 256) { of[i] = lWf[i]; om[i] = lWm[i]; }
}

// ---------------------------------------------------------------- K3g: reduce SUBS_ sub-partials -> WfT/WmT [n][8]
__global__ __launch_bounds__(256) void k3g_reduce(const float* __restrict__ Wpf,
                                                  const float* __restrict__ Wpm,
                                                  float* __restrict__ WfT,
                                                  float* __restrict__ WmT) {
    const int i = blockIdx.x * 256 + threadIdx.x;  // < N_*8
    if (i >= N_ * 8) return;
    const int n = i >> 3, b = i & 7;
    const int bucket = n / NPB_;
    const int rel = n - bucket * NPB_;
    float sf = 0.f, sm = 0.f;
#pragma unroll
    for (int sub = 0; sub < SUBS_; sub++) {
        const size_t off = ((size_t)bucket * SUBS_ + sub) * (NPB_ * 8) + rel * 8 + b;
        sf += Wpf[off];
        sm += Wpm[off];
    }
    WfT[i] = sf;
    WmT[i] = sm;
}

// ---------------------------------------------------------------- K4b: dense weighted sum over X
__global__ __launch_bounds__(256) void k4b_wsum(const float* __restrict__ X,
                                                const float* __restrict__ WmT,
                                                const float* __restrict__ WfT,
                                                float* __restrict__ gpart) {
    const int c = blockIdx.x;
    const int b = blockIdx.y;
    const int tx = threadIdx.x & 63;
    const int ty = threadIdx.x >> 6;
    const int npc = N_ / NCHUNK;
    const int n0 = c * npc;

    const float4* X4 = (const float4*)(X + (size_t)b * N_ * 256);
    float4 am = {0.f, 0.f, 0.f, 0.f};
    float4 af = {0.f, 0.f, 0.f, 0.f};

    for (int n = n0 + ty; n < n0 + npc; n += 4) {
        float wm = WmT[n * 8 + b];
        float wf = WfT[n * 8 + b];
        float4 v = X4[(size_t)n * 64 + tx];
        am.x = fmaf(wm, v.x, am.x); am.y = fmaf(wm, v.y, am.y);
        am.z = fmaf(wm, v.z, am.z); am.w = fmaf(wm, v.w, am.w);
        af.x = fmaf(wf, v.x, af.x); af.y = fmaf(wf, v.y, af.y);
        af.z = fmaf(wf, v.z, af.z); af.w = fmaf(wf, v.w, af.w);
    }

    __shared__ float4 red[256];
    red[threadIdx.x] = am;
    __syncthreads();
    if (ty == 0) {
        float4 r1 = red[tx + 64], r2 = red[tx + 128], r3 = red[tx + 192];
        am.x += r1.x + r2.x + r3.x; am.y += r1.y + r2.y + r3.y;
        am.z += r1.z + r2.z + r3.z; am.w += r1.w + r2.w + r3.w;
    }
    __syncthreads();
    red[threadIdx.x] = af;
    __syncthreads();
    if (ty == 0) {
        float4 r1 = red[tx + 64], r2 = red[tx + 128], r3 = red[tx + 192];
        af.x += r1.x + r2.x + r3.x; af.y += r1.y + r2.y + r3.y;
        af.z += r1.z + r2.z + r3.z; af.w += r1.w + r2.w + r3.w;
        float4* gp4 = (float4*)gpart;
        gp4[((c * 2 + 0) * 8 + b) * 64 + tx] = am;
        gp4[((c * 2 + 1) * 8 + b) * 64 + tx] = af;
    }
}

// ---------------------------------------------------------------- K5: finalize
__global__ __launch_bounds__(256) void k5_final(const float* __restrict__ gpart,
                                                const int* __restrict__ cnti,
                                                float* __restrict__ gf) {
    const int b = blockIdx.x;
    const int d = threadIdx.x;
    float sm = 0.f, sf = 0.f;
    for (int c = 0; c < NCHUNK; c++) {
        sm += gpart[((c * 2 + 0) * 8 + b) * 256 + d];
        sf += gpart[((c * 2 + 1) * 8 + b) * 256 + d];
    }
    const float cn = (float)cnti[b];
    gf[b * 256 + d] = (cn > 0.f) ? (sm / cn) : (sf / (float)N_);
}

// ---------------------------------------------------------------- launch
static inline char* align16(char* p) {
    return (char*)(((uintptr_t)p + 15) & ~(uintptr_t)15);
}

extern "C" void kernel_launch(void* const* d_in, const int* in_sizes, int n_in,
                              void* d_out, int out_size, void* d_ws, size_t ws_size,
                              hipStream_t stream) {
    const float* X     = (const float*)d_in[0];
    const float* eattr = (const float*)d_in[1];
    const float* W1    = (const float*)d_in[2];
    const float* b1    = (const float*)d_in[3];
    const float* W2    = (const float*)d_in[4];
    const float* b2    = (const float*)d_in[5];
    const int*   eidx_raw = (const int*)d_in[6];
    const unsigned char* mask8 = (const unsigned char*)d_in[7];
    const unsigned int*  mask32 = (const unsigned int*)d_in[7];

    float* out  = (float*)d_out;
    float* gf   = out;          // [B,D]
    float* wout = out + 2048;   // [B,E]

    // persistent region
    char* cur = (char*)d_ws;
    __half* ps_h = (__half*)cur;             cur += (size_t)N_ * 8 * 128 * 2;   // 20.48 MB  [b][n][128]
    __half* pd_h = (__half*)cur;             cur += (size_t)N_ * 8 * 128 * 2;
    __half* Wt   = (__half*)cur;             cur += 2 * 128 * 256 * 2;
    int* ce      = (int*)cur;                cur += 2 * E_ * 4;
    unsigned char* cmT = (unsigned char*)cur; cur += N_ * 8;
    cur = align16(cur);
    int* cnti    = (int*)cur;                cur += 8 * 4;
    cur = align16(cur);
    float* pmax  = (float*)cur;              cur += SB_ * 8 * 4;
    cur = align16(cur);
    double* psum = (double*)cur;             cur += SB_ * 8 * 8;
    float* gpart = (float*)cur;              cur += NCHUNK * 2 * 8 * 256 * 4;
    int* hpart   = (int*)cur;                cur += NB_ * BINS_ * 4;
    int* offsetG = (int*)cur;                cur += NB_ * BINS_ * 4;
    int* bstart  = (int*)cur;                cur += 32 * 4;
    cur = align16(cur);
    int4* esort  = (int4*)cur;               cur += (size_t)E_ * 16;
    int* rankB   = (int*)cur;                cur += E_ * 4;
    __half* b1h  = (__half*)cur;             cur += 128 * 2;
    __half* w2h  = (__half*)cur;             cur += 128 * 2;
    cur = align16(cur);
    float* scS   = (float*)cur;              cur += (size_t)E_ * 8 * 4;   // [b][pos]

    // overlay region (reuses ps_h: dead after k2/k3s... used only by k3ef/k3g/k4b)
    char* ocur = (char*)d_ws;
    float* Wpf = (float*)ocur;               ocur += (size_t)16 * SUBS_ * NPB_ * 8 * 4;  // 2.56 MB
    float* Wpm = (float*)ocur;               ocur += (size_t)16 * SUBS_ * NPB_ * 8 * 4;
    float* WfT = (float*)ocur;               ocur += N_ * 8 * 4;
    float* WmT = (float*)ocur;               ocur += N_ * 8 * 4;

    hipMemsetAsync(cnti, 0, 8 * sizeof(int), stream);
    hipLaunchKernelGGL(kprep, dim3(1250 + NB_), dim3(256), 0, stream,
                       eidx_raw, mask8, mask32, W1, b1, W2,
                       ce, cmT, Wt, b1h, w2h, cnti, hpart);
    hipLaunchKernelGGL(kprefix, dim3(1), dim3(256), 0, stream, hpart, offsetG, bstart);
    hipLaunchKernelGGL(k1_mfma, dim3(1250 + NB_), dim3(256), 0, stream,
                       X, Wt, ps_h, pd_h, ce, offsetG, esort, rankB);
    hipLaunchKernelGGL(k2_scores, dim3(E_ / 16), dim3(256), 0, stream,
                       ps_h, pd_h, esort, b1h, w2h, b2, eattr, scS);
    hipLaunchKernelGGL(k3s_stats, dim3(SB_), dim3(256), 0, stream, scS, pmax, psum);
    hipLaunchKernelGGL(k3ef, dim3(16 * SUBS_ + E_ / 256), dim3(256), 0, stream,
                       esort, scS, cmT, pmax, psum, bstart, rankB, Wpf, Wpm, wout);
    hipLaunchKernelGGL(k3g_reduce, dim3((N_ * 8 + 255) / 256), dim3(256), 0, stream,
                       Wpf, Wpm, WfT, WmT);
    hipLaunchKernelGGL(k4b_wsum, dim3(NCHUNK, 8), dim3(256), 0, stream, X, WmT, WfT, gpart);
    hipLaunchKernelGGL(k5_final, dim3(8), dim3(256), 0, stream, gpart, cnti, gf);
}